// Round 13
// baseline (474.062 us; speedup 1.0000x reference)
//
#include <hip/hip_runtime.h>
#include <hip/hip_bf16.h>
#include <math.h>

#define NN 30000
#define EE 400000
#define INP 128
#define HH 4
#define DD 64
#define CC 40
#define HD 256   // H*D
#define HC 160   // H*C

typedef unsigned short ushort;
typedef __attribute__((ext_vector_type(8))) short s8v;   // 8 x bf16 bits (4 VGPRs)
typedef __attribute__((ext_vector_type(4))) float f4v;   // MFMA accumulator

// Inputs: fp32 storage holding bf16-rounded values (established r1-r4).

__device__ inline ushort bf16_of_float(float f) {
    __hip_bfloat16 b = __float2bfloat16(f);
    return *(ushort*)&b;
}
// dword holding 2 packed bf16 -> 2 fp32 (low half, high half)
__device__ __forceinline__ float2 cvt2(unsigned d) {
    return make_float2(__uint_as_float(d << 16), __uint_as_float(d & 0xFFFF0000u));
}
__device__ __forceinline__ float b2f(ushort u) { return __uint_as_float(((unsigned)u) << 16); }

// float2 helpers (packable to v_pk_*_f32)
__device__ __forceinline__ float2 f2add(float2 a, float2 b){ return make_float2(a.x+b.x, a.y+b.y); }
__device__ __forceinline__ float2 f2mul(float2 a, float2 b){ return make_float2(a.x*b.x, a.y*b.y); }
__device__ __forceinline__ float2 f2muls(float2 a, float s){ return make_float2(a.x*s, a.y*s); }
__device__ __forceinline__ float2 f2max(float2 a, float2 b){ return make_float2(fmaxf(a.x,b.x), fmaxf(a.y,b.y)); }
__device__ __forceinline__ float2 f2fma(float2 a, float2 b, float2 c){
    return make_float2(__fmaf_rn(a.x,b.x,c.x), __fmaf_rn(a.y,b.y,c.y));
}

// async 16B global->LDS (dest = wave-uniform base + lane*16)
__device__ __forceinline__ void gld16(const void* g, void* l) {
    __builtin_amdgcn_global_load_lds((const __attribute__((address_space(1))) void*)g,
                                     (__attribute__((address_space(3))) void*)l, 16, 0, 0);
}

// 16-lane DPP row reductions (VALU-only)
__device__ __forceinline__ float rowsum16(float x) {
    int t;
    t = __builtin_amdgcn_update_dpp(0, __float_as_int(x), 0x128, 0xF, 0xF, false); x += __int_as_float(t);
    t = __builtin_amdgcn_update_dpp(0, __float_as_int(x), 0x124, 0xF, 0xF, false); x += __int_as_float(t);
    t = __builtin_amdgcn_update_dpp(0, __float_as_int(x), 0x122, 0xF, 0xF, false); x += __int_as_float(t);
    t = __builtin_amdgcn_update_dpp(0, __float_as_int(x), 0x121, 0xF, 0xF, false); x += __int_as_float(t);
    return x;
}
__device__ __forceinline__ float rowmax16(float x) {
    int t;
    t = __builtin_amdgcn_update_dpp(0, __float_as_int(x), 0x128, 0xF, 0xF, false); x = fmaxf(x, __int_as_float(t));
    t = __builtin_amdgcn_update_dpp(0, __float_as_int(x), 0x124, 0xF, 0xF, false); x = fmaxf(x, __int_as_float(t));
    t = __builtin_amdgcn_update_dpp(0, __float_as_int(x), 0x122, 0xF, 0xF, false); x = fmaxf(x, __int_as_float(t));
    t = __builtin_amdgcn_update_dpp(0, __float_as_int(x), 0x121, 0xF, 0xF, false); x = fmaxf(x, __int_as_float(t));
    return x;
}

// ---------------- fused prep: x-cast + weight transposes (packed bt2) + zeroing + small vecs ----------------
#define XB 3750   // ceil(960000/256)
#define TB 1408   // ceil(360448/256)
#define ZB 239    // ceil(61024/256)

__global__ __launch_bounds__(256) void k_prep(const float* __restrict__ x, ushort* __restrict__ xc,
        const float* W0, const float* W1, const float* W2, const float* W3,
        const float* W4, const float* W5, const float* W6, const float* W7,
        ushort* bt0, ushort* bt1, ushort* bt2,
        int* __restrict__ zero_region,
        const float* b0, const float* a0, const float* b1, const float* a1,
        const float* b2, const float* a2, const float* g0, const float* be0,
        const float* g1, const float* be1, ushort* __restrict__ smallv) {
    int b = blockIdx.x, t = threadIdx.x;
    if (b < XB) {
        int i = b * 256 + t;
        if (i < NN * INP / 4) {
            float4 v = ((const float4*)x)[i];
            ushort4 o;
            o.x = bf16_of_float(v.x); o.y = bf16_of_float(v.y);
            o.z = bf16_of_float(v.z); o.w = bf16_of_float(v.w);
            ((ushort4*)xc)[i] = o;
        }
    } else if (b < XB + TB) {
        const float* Ws[8] = {W0, W1, W2, W3, W4, W5, W6, W7};
        int g = (b - XB) * 256 + t;               // < 360448
        if (g < 98304) {                          // bt0: 3 segs of [256 x 128]
            int seg = g >> 15, local = g & 32767;
            int n = local >> 7, k = local & 127;
            bt0[g] = bf16_of_float(Ws[seg][k * 256 + n]);
        } else if (g < 229376) {                  // bt1: 2 segs of [256 x 256]
            int gg = g - 98304;
            int seg = gg >> 16, local = gg & 65535;
            int n = local >> 8, k = local & 255;
            bt1[gg] = bf16_of_float(Ws[3 + seg][k * 256 + n]);
        } else if (g < 360448) {                  // bt2: packed [512 x 256], rows = 3x160 + 32 pad
            int gg = g - 229376;
            int n = gg >> 8, k = gg & 255;
            ushort val = 0;
            if (n < 480) {
                int seg = n / 160;
                int nn = n - seg * 160;
                val = bf16_of_float(Ws[5 + seg][k * 160 + nn]);
            }
            bt2[gg] = val;
        }
    } else if (b < XB + TB + ZB) {
        int i = (b - XB - TB) * 256 + t;
        if (i < 1024 + 2 * NN) zero_region[i] = 0;   // bnstats + cnt + pos
    } else {
        const float* ptrs[10] = {b0, a0, b1, a1, b2, a2, g0, be0, g1, be1};
        const int sz[10] = {256, 256, 256, 256, 160, 160, 256, 256, 256, 256};
        int off = 0;
        for (int j = 0; j < 10; j++) {
            if (t < sz[j]) smallv[off + t] = bf16_of_float(ptrs[j][t]);
            off += sz[j];
        }
    }
}

// ---------------- CSR build ----------------

__global__ __launch_bounds__(256) void k_hist(const int* __restrict__ dst, int* __restrict__ cnt) {
    int e = blockIdx.x * 256 + threadIdx.x;
    if (e < EE) atomicAdd(&cnt[dst[e]], 1);
}

// scan + descending-degree counting sort (order[] = nodes sorted by degree, high first).
// Sorting makes the 4 waves of each aggregate block near-equal work (kills the
// Poisson max-of-4 tail, ~50% overhead at lambda~13).
__global__ __launch_bounds__(1024) void k_scan(const int* __restrict__ cnt, int* __restrict__ indptr,
                                               int* __restrict__ order) {
    __shared__ int ss[1024];
    __shared__ int bins[64];
    __shared__ int binpos[64];
    int t = threadIdx.x;
    if (t < 64) bins[t] = 0;
    const int CH = 30;
    int b = t * CH;
    int e2 = min(NN, b + CH);
    int s = 0;
    for (int i = b; i < e2; i++) s += cnt[i];
    ss[t] = s;
    __syncthreads();
    for (int i = b; i < e2; i++) {
        int dg = min(cnt[i], 63);
        atomicAdd(&bins[63 - dg], 1);             // descending degree
    }
    for (int o = 1; o < 1024; o <<= 1) {
        int v = (t >= o) ? ss[t - o] : 0;
        __syncthreads();
        ss[t] += v;
        __syncthreads();
    }
    int run = ss[t] - s;
    for (int i = b; i < e2; i++) { indptr[i] = run; run += cnt[i]; }
    if (t == 0) {
        indptr[NN] = EE;
        int acc = 0;
        for (int k = 0; k < 64; k++) { binpos[k] = acc; acc += bins[k]; }
    }
    __syncthreads();
    for (int i = b; i < e2; i++) {
        int dg = min(cnt[i], 63);
        int p = atomicAdd(&binpos[63 - dg], 1);
        order[p] = i;
    }
}

__global__ __launch_bounds__(256) void k_scatter(const int* __restrict__ src, const int* __restrict__ dst,
                                                 const int* __restrict__ indptr, int* __restrict__ pos,
                                                 int* __restrict__ srcs) {
    int e = blockIdx.x * 256 + threadIdx.x;
    if (e < EE) {
        int d = dst[e];
        int p = atomicAdd(&pos[d], 1);
        srcs[indptr[d] + p] = src[e];
    }
}

// ---------------- tiled bf16 MFMA GEMM, single-buffer staging (r10-proven) ----------------
// 128x128 tile, 4 waves, BK=32. MFMA operands SWAPPED (bg, af): acc holds the
// transposed fragment -- lane&15 = output ROW, regs = 4 consecutive output COLS
// -> each acc[i][c] packs to one ushort4 store (16 stores/lane vs 64).

template<int K, int SEGW, int NSEG>
__global__ __launch_bounds__(256) void k_gemm_tiled(const ushort* __restrict__ A,
                                                    const ushort* __restrict__ Bt,
                                                    ushort* __restrict__ o0, ushort* __restrict__ o1,
                                                    ushort* __restrict__ o2) {
    __shared__ ushort As[128 * 32];   // chunk c (16B) at byte c*16; row = c>>2, kpart = c&3
    __shared__ ushort Bs[128 * 32];
    int t = threadIdx.x;
    int wave = t >> 6, lane = t & 63;
    int m = lane & 15, q = lane >> 4;
    int row0 = blockIdx.x * 128, col0 = blockIdx.y * 128;
    int wr = (wave >> 1) << 6, wc = (wave & 1) << 6;
    f4v acc[4][4] = {};
    int c1 = t, c2 = t + 256;
    int ar1 = min(row0 + (c1 >> 2), NN - 1);
    int ar2 = min(row0 + (c2 >> 2), NN - 1);
    const ushort* a1 = A + (size_t)ar1 * K + (c1 & 3) * 8;
    const ushort* a2 = A + (size_t)ar2 * K + (c2 & 3) * 8;
    const ushort* b1 = Bt + (size_t)(col0 + (c1 >> 2)) * K + (c1 & 3) * 8;
    const ushort* b2 = Bt + (size_t)(col0 + (c2 >> 2)) * K + (c2 & 3) * 8;
    int wbase = wave << 10;
    char* AsB = (char*)As;
    char* BsB = (char*)Bs;

#pragma unroll
    for (int kt = 0; kt < K; kt += 32) {
        __syncthreads();
        gld16(a1 + kt, AsB + wbase);
        gld16(a2 + kt, AsB + 4096 + wbase);
        gld16(b1 + kt, BsB + wbase);
        gld16(b2 + kt, BsB + 4096 + wbase);
        __syncthreads();
        s8v af[4], bg[4];
#pragma unroll
        for (int i = 0; i < 4; i++) af[i] = *(const s8v*)&As[(wr + i * 16 + m) * 32 + q * 8];
#pragma unroll
        for (int c = 0; c < 4; c++) bg[c] = *(const s8v*)&Bs[(wc + c * 16 + m) * 32 + q * 8];
#pragma unroll
        for (int i = 0; i < 4; i++)
#pragma unroll
            for (int c = 0; c < 4; c++)   // SWAPPED operands: acc holds C^T fragment
                acc[i][c] = __builtin_amdgcn_mfma_f32_16x16x32_bf16(bg[c], af[i], acc[i][c], 0, 0, 0);
    }

    // epilogue: value(lane,reg r) = C[row0+wr+i*16+m][col0+wc+c*16+q*4+r]
#pragma unroll
    for (int c = 0; c < 4; c++) {
        int gcb = col0 + wc + c * 16;             // 16-col tile: SEGW mult of 16 => single segment
        if (gcb < SEGW * NSEG) {
            int seg = gcb / SEGW;
            int colb = gcb - seg * SEGW + q * 4;  // + r (r=0..3 contiguous)
            ushort* op = seg == 0 ? o0 : (seg == 1 ? o1 : o2);
#pragma unroll
            for (int i = 0; i < 4; i++) {
                int gr = row0 + wr + i * 16 + m;
                if (gr < NN) {
                    ushort4 s4;
                    s4.x = bf16_of_float(acc[i][c][0]);
                    s4.y = bf16_of_float(acc[i][c][1]);
                    s4.z = bf16_of_float(acc[i][c][2]);
                    s4.w = bf16_of_float(acc[i][c][3]);
                    *(ushort4*)&op[(size_t)gr * SEGW + colb] = s4;
                }
            }
        }
    }
}

// ---------------- fused GATv2 edge phase (+ final log-softmax), degree-sorted ----------------
// One wave per dst node (taken from order[]), all 4 heads. lane=16h+j holds dims
// [4j..4j+3] of head h. All features bf16. attn pre-scaled by log2(e) -> exp2f.
// NO readfirstlane on srcs (r11); NO fused BN stats (r9).

template<int DH, bool FINAL>
__global__ __launch_bounds__(256) void k_aggregate(const ushort* __restrict__ fs, const ushort* __restrict__ fd,
                                                   const ushort* __restrict__ res,
                                                   const ushort* __restrict__ attn,
                                                   const ushort* __restrict__ bias,
                                                   const int* __restrict__ indptr, const int* __restrict__ srcs,
                                                   const int* __restrict__ order,
                                                   ushort* __restrict__ outb, float* __restrict__ outf) {
    constexpr int F = HH * DH;
    constexpr int JMAX = DH >> 2;
    int tt = threadIdx.x;
    int v = __builtin_amdgcn_readfirstlane(order[blockIdx.x * 4 + (tt >> 6)]);
    int lane = tt & 63;
    int h = lane >> 4, j = lane & 15;
    bool act = j < JMAX;
    unsigned off = h * DH + 4 * j;
    unsigned vbase = (unsigned)v * F + off;
    float2 fda = {0.f,0.f}, fdb = {0.f,0.f}, ava = {0.f,0.f}, avb = {0.f,0.f};
    if (act) {
        uint2 d = *(const uint2*)&fd[vbase];
        fda = cvt2(d.x); fdb = cvt2(d.y);
        uint2 a = *(const uint2*)&attn[off];
        const float LOG2E = 1.4426950408889634f;
        ava = f2muls(cvt2(a.x), LOG2E); avb = f2muls(cvt2(a.y), LOG2E);
    }
    float l = 0.f;
    float2 acca = {0.f,0.f}, accb = {0.f,0.f};
    int beg = indptr[v], end = indptr[v + 1];

    auto ldrow = [&](int u, float2& ra, float2& rb) {
        ra = make_float2(0.f, 0.f); rb = make_float2(0.f, 0.f);
        if (act) {
            uint2 d = *(const uint2*)&fs[(unsigned)u * F + off];
            ra = cvt2(d.x); rb = cvt2(d.y);
        }
    };
    auto dotlr = [&](const float2& ra, const float2& rb) -> float {
        float2 t0 = f2add(ra, fda);
        float2 t1 = f2add(rb, fdb);
        t0 = f2max(t0, f2muls(t0, 0.2f));      // leaky_relu slope 0.2 == max(t, 0.2t)
        t1 = f2max(t1, f2muls(t1, 0.2f));
        float2 p2 = f2mul(ava, t0);
        p2 = f2fma(avb, t1, p2);
        return p2.x + p2.y;                    // log2-domain score
    };

    int i = beg;
    for (; i + 3 < end; i += 4) {
        int u0 = srcs[i], u1 = srcs[i+1], u2 = srcs[i+2], u3 = srcs[i+3];
        float2 r0a, r0b, r1a, r1b, r2a, r2b, r3a, r3b;
        ldrow(u0, r0a, r0b); ldrow(u1, r1a, r1b);
        ldrow(u2, r2a, r2b); ldrow(u3, r3a, r3b);
        float p0 = rowsum16(dotlr(r0a, r0b));
        float p1 = rowsum16(dotlr(r1a, r1b));
        float p2 = rowsum16(dotlr(r2a, r2b));
        float p3 = rowsum16(dotlr(r3a, r3b));
        float w0 = exp2f(p0), w1 = exp2f(p1), w2 = exp2f(p2), w3 = exp2f(p3);
        l += (w0 + w1) + (w2 + w3);
        acca = f2fma(make_float2(w0, w0), r0a, acca);
        accb = f2fma(make_float2(w0, w0), r0b, accb);
        acca = f2fma(make_float2(w1, w1), r1a, acca);
        accb = f2fma(make_float2(w1, w1), r1b, accb);
        acca = f2fma(make_float2(w2, w2), r2a, acca);
        accb = f2fma(make_float2(w2, w2), r2b, accb);
        acca = f2fma(make_float2(w3, w3), r3a, acca);
        accb = f2fma(make_float2(w3, w3), r3b, accb);
    }
    for (; i < end; i++) {
        float2 ra, rb;
        ldrow(srcs[i], ra, rb);
        float p0 = rowsum16(dotlr(ra, rb));
        float w0 = exp2f(p0);
        l += w0;
        acca = f2fma(make_float2(w0, w0), ra, acca);
        accb = f2fma(make_float2(w0, w0), rb, accb);
    }

    float4 o4 = {0.f, 0.f, 0.f, 0.f};
    if (act) {
        float inv = 1.f / fmaxf(l, 1e-9f);
        uint2 rr = *(const uint2*)&res[vbase];
        float2 rl = cvt2(rr.x), rh = cvt2(rr.y);
        uint2 bb = *(const uint2*)&bias[off];
        float2 bl = cvt2(bb.x), bh = cvt2(bb.y);
        o4.x = acca.x * inv + rl.x + bl.x;
        o4.y = acca.y * inv + rl.y + bl.y;
        o4.z = accb.x * inv + rh.x + bh.x;
        o4.w = accb.y * inv + rh.y + bh.y;
        if (!FINAL) {
            o4.x = fmaxf(o4.x, 0.f); o4.y = fmaxf(o4.y, 0.f);
            o4.z = fmaxf(o4.z, 0.f); o4.w = fmaxf(o4.w, 0.f);
        }
    }
    if (!FINAL) {
        if (act) {
            ushort4 s4;
            s4.x = bf16_of_float(o4.x); s4.y = bf16_of_float(o4.y);
            s4.z = bf16_of_float(o4.z); s4.w = bf16_of_float(o4.w);
            *(ushort4*)&outb[vbase] = s4;
        }
    } else {
        // head mean: sum over the 4 head groups (lanes 16/32 apart, same j)
#pragma unroll
        for (int msk = 16; msk <= 32; msk <<= 1) {
            o4.x += __shfl_xor(o4.x, msk, 64);
            o4.y += __shfl_xor(o4.y, msk, 64);
            o4.z += __shfl_xor(o4.z, msk, 64);
            o4.w += __shfl_xor(o4.w, msk, 64);
        }
        float4 zv = make_float4(0.25f * o4.x, 0.25f * o4.y, 0.25f * o4.z, 0.25f * o4.w);
        float mx4 = act ? fmaxf(fmaxf(zv.x, zv.y), fmaxf(zv.z, zv.w)) : -1e30f;
        float mx = rowmax16(mx4);
        float es = 0.f;
        if (act) es = __expf(zv.x - mx) + __expf(zv.y - mx) + __expf(zv.z - mx) + __expf(zv.w - mx);
        float ssum = rowsum16(es);
        float lse = mx + logf(ssum);
        if (act && h == 0) {
            float4 w4 = make_float4(zv.x - lse, zv.y - lse, zv.z - lse, zv.w - lse);
            *(float4*)&outf[(size_t)v * CC + 4 * j] = w4;
        }
    }
}

// ---------------- batchnorm stats (bf16 in), r8-proven structure: 60k global atomics ----------------

__global__ __launch_bounds__(256) void k_bn_partial(const ushort* __restrict__ h, float* __restrict__ sum,
                                                    float* __restrict__ sumsq) {
    int c = threadIdx.x;
    int r0 = blockIdx.x * 128;
    int r1 = min(NN, r0 + 128);
    float s = 0.f, ss = 0.f;
    for (int r = r0; r < r1; r++) {
        float vv = b2f(h[(size_t)r * HD + c]);
        s += vv; ss += vv * vv;
    }
    atomicAdd(&sum[c], s);
    atomicAdd(&sumsq[c], ss);
}

// ---------------- batchnorm normalize (bf16 in, bf16 out), x4 vectorized ----------------

__global__ __launch_bounds__(256) void k_bn_norm(const ushort* __restrict__ hin, const float* __restrict__ sum,
                                                 const float* __restrict__ sumsq,
                                                 const ushort* __restrict__ g,
                                                 const ushort* __restrict__ be,
                                                 ushort* __restrict__ hbf) {
    int i4 = blockIdx.x * 256 + threadIdx.x;
    if (i4 < NN * HD / 4) {
        int base = i4 * 4;
        int c = base & (HD - 1);
        ushort4 hv = ((const ushort4*)hin)[i4];
        ushort4 ov;
        float vv[4] = {b2f(hv.x), b2f(hv.y), b2f(hv.z), b2f(hv.w)};
        ushort* po = (ushort*)&ov;
#pragma unroll
        for (int k = 0; k < 4; k++) {
            float mean = sum[c + k] * (1.0f / NN);
            float var = fmaxf(sumsq[c + k] * (1.0f / NN) - mean * mean, 0.f);
            float y = b2f(g[c + k]) * (vv[k] - mean) * rsqrtf(var + 1e-5f) + b2f(be[c + k]);
            po[k] = bf16_of_float(fmaxf(y, 0.f));
        }
        ((ushort4*)hbf)[i4] = ov;
    }
}

// ---------------- driver ----------------

static inline char* alignup(char* p) { return (char*)(((size_t)p + 255) & ~(size_t)255); }

extern "C" void kernel_launch(void* const* d_in, const int* in_sizes, int n_in,
                              void* d_out, int out_size, void* d_ws, size_t ws_size,
                              hipStream_t stream) {
    const float* x     = (const float*)d_in[0];
    const int*  src    = (const int*)d_in[1];
    const int*  dst    = (const int*)d_in[2];
    const float* Wsrc0 = (const float*)d_in[3];
    const float* Wdst0 = (const float*)d_in[4];
    const float* b0    = (const float*)d_in[5];
    const float* attn0 = (const float*)d_in[6];
    const float* resW0 = (const float*)d_in[7];
    const float* Wsrc1 = (const float*)d_in[8];
    const float* Wdst1 = (const float*)d_in[9];
    const float* b1    = (const float*)d_in[10];
    const float* attn1 = (const float*)d_in[11];
    const float* Wsrc2 = (const float*)d_in[12];
    const float* Wdst2 = (const float*)d_in[13];
    const float* b2    = (const float*)d_in[14];
    const float* attn2 = (const float*)d_in[15];
    const float* resW2 = (const float*)d_in[16];
    const float* g0    = (const float*)d_in[17];
    const float* be0   = (const float*)d_in[18];
    const float* g1    = (const float*)d_in[19];
    const float* be1   = (const float*)d_in[20];

    char* w = (char*)d_ws;
    const size_t NF = (size_t)NN * HD;
    ushort* fsb = (ushort*)w; w += NF * 2;
    ushort* fdb = (ushort*)w; w += NF * 2;
    ushort* resb= (ushort*)w; w += NF * 2;
    ushort* hag = (ushort*)w; w += NF * 2;
    ushort* hbf = (ushort*)w; w += NF * 2;
    ushort* xc  = (ushort*)w; w += (size_t)NN * INP * 2;
    ushort* bt0 = (ushort*)w; w += 768 * 128 * 2;   // 3 segs [256x128]
    ushort* bt1 = (ushort*)w; w += 512 * 256 * 2;   // 2 segs [256x256]
    ushort* bt2 = (ushort*)w; w += 512 * 256 * 2;   // packed 3x160 + 32 pad rows, K=256
    ushort* smallv = (ushort*)w; w += 2368 * 2; w = alignup(w);
    // zeroed in k_prep: bnstats[1024] + cnt[NN] + pos[NN] (contiguous)
    float* bnstats = (float*)w; w += 1024 * 4;
    int* cnt    = (int*)w; w += NN * 4;
    int* pos    = (int*)w; w += NN * 4; w = alignup(w);
    int* indptr = (int*)w; w += (NN + 1) * 4; w = alignup(w);
    int* order  = (int*)w; w += NN * 4; w = alignup(w);
    int* srcs   = (int*)w; w += EE * 4;

    const ushort* c_b0    = smallv + 0;
    const ushort* c_attn0 = smallv + 256;
    const ushort* c_b1    = smallv + 512;
    const ushort* c_attn1 = smallv + 768;
    const ushort* c_b2    = smallv + 1024;
    const ushort* c_attn2 = smallv + 1184;
    const ushort* c_g0    = smallv + 1344;
    const ushort* c_be0   = smallv + 1600;
    const ushort* c_g1    = smallv + 1856;
    const ushort* c_be1   = smallv + 2112;

    // 1: fused prep
    k_prep<<<XB + TB + ZB + 1, 256, 0, stream>>>(x, xc,
        Wsrc0, Wdst0, resW0, Wsrc1, Wdst1, Wsrc2, Wdst2, resW2, bt0, bt1, bt2,
        (int*)bnstats,
        b0, attn0, b1, attn1, b2, attn2, g0, be0, g1, be1, smallv);

    // 2-4: CSR build + degree sort
    k_hist<<<(EE + 255) / 256, 256, 0, stream>>>(dst, cnt);
    k_scan<<<1, 1024, 0, stream>>>(cnt, indptr, order);
    k_scatter<<<(EE + 255) / 256, 256, 0, stream>>>(src, dst, indptr, pos, srcs);

    const int MB = (NN + 127) / 128;   // 235

    // 5-8: layer 0
    k_gemm_tiled<128, 256, 3><<<dim3(MB, 6), 256, 0, stream>>>(xc, bt0, fsb, fdb, resb);
    k_aggregate<DD, false><<<NN / 4, 256, 0, stream>>>(fsb, fdb, resb, c_attn0, c_b0,
        indptr, srcs, order, hag, nullptr);
    k_bn_partial<<<MB, 256, 0, stream>>>(hag, bnstats, bnstats + 256);
    k_bn_norm<<<(int)((NF / 4 + 255) / 256), 256, 0, stream>>>(hag, bnstats, bnstats + 256,
                                                               c_g0, c_be0, hbf);

    // 9-12: layer 1 (identity residual = hbf)
    k_gemm_tiled<256, 256, 2><<<dim3(MB, 4), 256, 0, stream>>>(hbf, bt1, fsb, fdb, nullptr);
    k_aggregate<DD, false><<<NN / 4, 256, 0, stream>>>(fsb, fdb, hbf, c_attn1, c_b1,
        indptr, srcs, order, hag, nullptr);
    k_bn_partial<<<MB, 256, 0, stream>>>(hag, bnstats + 512, bnstats + 768);
    k_bn_norm<<<(int)((NF / 4 + 255) / 256), 256, 0, stream>>>(hag, bnstats + 512, bnstats + 768,
                                                               c_g1, c_be1, hbf);

    // 13-14: layer 2 (packed 160-col segments) + fused head-mean/log_softmax -> d_out
    k_gemm_tiled<256, 160, 3><<<dim3(MB, 4), 256, 0, stream>>>(hbf, bt2, fsb, fdb, resb);
    k_aggregate<CC, true><<<NN / 4, 256, 0, stream>>>(fsb, fdb, resb, c_attn2, c_b2,
        indptr, srcs, order, nullptr, (float*)d_out);
}

// Round 15
// 445.889 us; speedup vs baseline: 1.0632x; 1.0632x over previous
//
#include <hip/hip_runtime.h>
#include <hip/hip_bf16.h>
#include <math.h>

#define NN 30000
#define EE 400000
#define INP 128
#define HH 4
#define DD 64
#define CC 40
#define HD 256   // H*D
#define HC 160   // H*C

typedef unsigned short ushort;
typedef __attribute__((ext_vector_type(8))) short s8v;   // 8 x bf16 bits (4 VGPRs)
typedef __attribute__((ext_vector_type(4))) float f4v;   // MFMA accumulator

// Inputs: fp32 storage holding bf16-rounded values (established r1-r4).

__device__ inline ushort bf16_of_float(float f) {
    __hip_bfloat16 b = __float2bfloat16(f);
    return *(ushort*)&b;
}
// dword holding 2 packed bf16 -> 2 fp32 (low half, high half)
__device__ __forceinline__ float2 cvt2(unsigned d) {
    return make_float2(__uint_as_float(d << 16), __uint_as_float(d & 0xFFFF0000u));
}
__device__ __forceinline__ float b2f(ushort u) { return __uint_as_float(((unsigned)u) << 16); }

// float2 helpers (packable to v_pk_*_f32)
__device__ __forceinline__ float2 f2add(float2 a, float2 b){ return make_float2(a.x+b.x, a.y+b.y); }
__device__ __forceinline__ float2 f2mul(float2 a, float2 b){ return make_float2(a.x*b.x, a.y*b.y); }
__device__ __forceinline__ float2 f2muls(float2 a, float s){ return make_float2(a.x*s, a.y*s); }
__device__ __forceinline__ float2 f2max(float2 a, float2 b){ return make_float2(fmaxf(a.x,b.x), fmaxf(a.y,b.y)); }
__device__ __forceinline__ float2 f2fma(float2 a, float2 b, float2 c){
    return make_float2(__fmaf_rn(a.x,b.x,c.x), __fmaf_rn(a.y,b.y,c.y));
}

// async 16B global->LDS (dest = wave-uniform base + lane*16)
__device__ __forceinline__ void gld16(const void* g, void* l) {
    __builtin_amdgcn_global_load_lds((const __attribute__((address_space(1))) void*)g,
                                     (__attribute__((address_space(3))) void*)l, 16, 0, 0);
}

// 16-lane DPP row reductions (VALU-only)
__device__ __forceinline__ float rowsum16(float x) {
    int t;
    t = __builtin_amdgcn_update_dpp(0, __float_as_int(x), 0x128, 0xF, 0xF, false); x += __int_as_float(t);
    t = __builtin_amdgcn_update_dpp(0, __float_as_int(x), 0x124, 0xF, 0xF, false); x += __int_as_float(t);
    t = __builtin_amdgcn_update_dpp(0, __float_as_int(x), 0x122, 0xF, 0xF, false); x += __int_as_float(t);
    t = __builtin_amdgcn_update_dpp(0, __float_as_int(x), 0x121, 0xF, 0xF, false); x += __int_as_float(t);
    return x;
}
__device__ __forceinline__ float rowmax16(float x) {
    int t;
    t = __builtin_amdgcn_update_dpp(0, __float_as_int(x), 0x128, 0xF, 0xF, false); x = fmaxf(x, __int_as_float(t));
    t = __builtin_amdgcn_update_dpp(0, __float_as_int(x), 0x124, 0xF, 0xF, false); x = fmaxf(x, __int_as_float(t));
    t = __builtin_amdgcn_update_dpp(0, __float_as_int(x), 0x122, 0xF, 0xF, false); x = fmaxf(x, __int_as_float(t));
    t = __builtin_amdgcn_update_dpp(0, __float_as_int(x), 0x121, 0xF, 0xF, false); x = fmaxf(x, __int_as_float(t));
    return x;
}

// ---------------- fused prep: x-cast + weight transposes (packed bt2) + zeroing + small vecs ----------------
#define XB 3750   // ceil(960000/256)
#define TB 1408   // ceil(360448/256)
#define ZB 240    // ceil((1024+2*NN+128)/256)

__global__ __launch_bounds__(256) void k_prep(const float* __restrict__ x, ushort* __restrict__ xc,
        const float* W0, const float* W1, const float* W2, const float* W3,
        const float* W4, const float* W5, const float* W6, const float* W7,
        ushort* bt0, ushort* bt1, ushort* bt2,
        int* __restrict__ zero_region,
        const float* b0, const float* a0, const float* b1, const float* a1,
        const float* b2, const float* a2, const float* g0, const float* be0,
        const float* g1, const float* be1, ushort* __restrict__ smallv) {
    int b = blockIdx.x, t = threadIdx.x;
    if (b < XB) {
        int i = b * 256 + t;
        if (i < NN * INP / 4) {
            float4 v = ((const float4*)x)[i];
            ushort4 o;
            o.x = bf16_of_float(v.x); o.y = bf16_of_float(v.y);
            o.z = bf16_of_float(v.z); o.w = bf16_of_float(v.w);
            ((ushort4*)xc)[i] = o;
        }
    } else if (b < XB + TB) {
        const float* Ws[8] = {W0, W1, W2, W3, W4, W5, W6, W7};
        int g = (b - XB) * 256 + t;               // < 360448
        if (g < 98304) {                          // bt0: 3 segs of [256 x 128]
            int seg = g >> 15, local = g & 32767;
            int n = local >> 7, k = local & 127;
            bt0[g] = bf16_of_float(Ws[seg][k * 256 + n]);
        } else if (g < 229376) {                  // bt1: 2 segs of [256 x 256]
            int gg = g - 98304;
            int seg = gg >> 16, local = gg & 65535;
            int n = local >> 8, k = local & 255;
            bt1[gg] = bf16_of_float(Ws[3 + seg][k * 256 + n]);
        } else if (g < 360448) {                  // bt2: packed [512 x 256], rows = 3x160 + 32 pad
            int gg = g - 229376;
            int n = gg >> 8, k = gg & 255;
            ushort val = 0;
            if (n < 480) {
                int seg = n / 160;
                int nn = n - seg * 160;
                val = bf16_of_float(Ws[5 + seg][k * 160 + nn]);
            }
            bt2[gg] = val;
        }
    } else if (b < XB + TB + ZB) {
        int i = (b - XB - TB) * 256 + t;
        if (i < 1024 + 2 * NN + 128) zero_region[i] = 0;   // bnstats + cnt + pos + binCnt + binRes
    } else {
        const float* ptrs[10] = {b0, a0, b1, a1, b2, a2, g0, be0, g1, be1};
        const int sz[10] = {256, 256, 256, 256, 160, 160, 256, 256, 256, 256};
        int off = 0;
        for (int j = 0; j < 10; j++) {
            if (t < sz[j]) smallv[off + t] = bf16_of_float(ptrs[j][t]);
            off += sz[j];
        }
    }
}

// ---------------- CSR build + cheap parallel degree sort ----------------

__global__ __launch_bounds__(256) void k_hist(const int* __restrict__ dst, int* __restrict__ cnt) {
    int e = blockIdx.x * 256 + threadIdx.x;
    if (e < EE) atomicAdd(&cnt[dst[e]], 1);
}

// phase A: global 64-bin degree histogram (LDS pre-aggregated; <=64 global atomics/block)
__global__ __launch_bounds__(256) void k_binhist(const int* __restrict__ cnt, int* __restrict__ binCnt) {
    __shared__ int lb[64];
    int t = threadIdx.x;
    if (t < 64) lb[t] = 0;
    __syncthreads();
    int i = blockIdx.x * 256 + t;
    if (i < NN) atomicAdd(&lb[63 - min(cnt[i], 63)], 1);   // bin 0 = highest degree
    __syncthreads();
    if (t < 64 && lb[t] > 0) atomicAdd(&binCnt[t], lb[t]);
}

// indptr prefix (r12-cheap) + trivial 64-bin prefix for the sort bases
__global__ __launch_bounds__(1024) void k_scan(const int* __restrict__ cnt, int* __restrict__ indptr,
                                               const int* __restrict__ binCnt, int* __restrict__ binRes) {
    __shared__ int ss[1024];
    int t = threadIdx.x;
    const int CH = 30;
    int b = t * CH;
    int e2 = min(NN, b + CH);
    int s = 0;
    for (int i = b; i < e2; i++) s += cnt[i];
    ss[t] = s;
    __syncthreads();
    for (int o = 1; o < 1024; o <<= 1) {
        int v = (t >= o) ? ss[t - o] : 0;
        __syncthreads();
        ss[t] += v;
        __syncthreads();
    }
    int run = ss[t] - s;
    for (int i = b; i < e2; i++) { indptr[i] = run; run += cnt[i]; }
    if (t == 0) {
        indptr[NN] = EE;
        int acc = 0;
        for (int k = 0; k < 64; k++) { binRes[k] = acc; acc += binCnt[k]; }
    }
}

// phase B: place nodes into order[] (block-local ranks + one range-reservation atomic per bin)
__global__ __launch_bounds__(256) void k_order(const int* __restrict__ cnt, int* __restrict__ binRes,
                                               int* __restrict__ order) {
    __shared__ int lb[64], lbase[64];
    int t = threadIdx.x;
    if (t < 64) lb[t] = 0;
    __syncthreads();
    int i = blockIdx.x * 256 + t;
    int bin = 0, rank = 0;
    if (i < NN) {
        bin = 63 - min(cnt[i], 63);
        rank = atomicAdd(&lb[bin], 1);
    }
    __syncthreads();
    if (t < 64 && lb[t] > 0) lbase[t] = atomicAdd(&binRes[t], lb[t]);
    __syncthreads();
    if (i < NN) order[lbase[bin] + rank] = i;
}

__global__ __launch_bounds__(256) void k_scatter(const int* __restrict__ src, const int* __restrict__ dst,
                                                 const int* __restrict__ indptr, int* __restrict__ pos,
                                                 int* __restrict__ srcs) {
    int e = blockIdx.x * 256 + threadIdx.x;
    if (e < EE) {
        int d = dst[e];
        int p = atomicAdd(&pos[d], 1);
        srcs[indptr[d] + p] = src[e];
    }
}

// ---------------- tiled bf16 MFMA GEMM, single-buffer staging (r10-proven) ----------------
// 128x128 tile, 4 waves, BK=32. MFMA operands SWAPPED (bg, af): acc holds the
// transposed fragment -- lane&15 = output ROW, regs = 4 consecutive output COLS
// -> each acc[i][c] packs to one ushort4 store (16 stores/lane vs 64).

template<int K, int SEGW, int NSEG>
__global__ __launch_bounds__(256) void k_gemm_tiled(const ushort* __restrict__ A,
                                                    const ushort* __restrict__ Bt,
                                                    ushort* __restrict__ o0, ushort* __restrict__ o1,
                                                    ushort* __restrict__ o2) {
    __shared__ ushort As[128 * 32];   // chunk c (16B) at byte c*16; row = c>>2, kpart = c&3
    __shared__ ushort Bs[128 * 32];
    int t = threadIdx.x;
    int wave = t >> 6, lane = t & 63;
    int m = lane & 15, q = lane >> 4;
    int row0 = blockIdx.x * 128, col0 = blockIdx.y * 128;
    int wr = (wave >> 1) << 6, wc = (wave & 1) << 6;
    f4v acc[4][4] = {};
    int c1 = t, c2 = t + 256;
    int ar1 = min(row0 + (c1 >> 2), NN - 1);
    int ar2 = min(row0 + (c2 >> 2), NN - 1);
    const ushort* a1 = A + (size_t)ar1 * K + (c1 & 3) * 8;
    const ushort* a2 = A + (size_t)ar2 * K + (c2 & 3) * 8;
    const ushort* b1 = Bt + (size_t)(col0 + (c1 >> 2)) * K + (c1 & 3) * 8;
    const ushort* b2 = Bt + (size_t)(col0 + (c2 >> 2)) * K + (c2 & 3) * 8;
    int wbase = wave << 10;
    char* AsB = (char*)As;
    char* BsB = (char*)Bs;

#pragma unroll
    for (int kt = 0; kt < K; kt += 32) {
        __syncthreads();
        gld16(a1 + kt, AsB + wbase);
        gld16(a2 + kt, AsB + 4096 + wbase);
        gld16(b1 + kt, BsB + wbase);
        gld16(b2 + kt, BsB + 4096 + wbase);
        __syncthreads();
        s8v af[4], bg[4];
#pragma unroll
        for (int i = 0; i < 4; i++) af[i] = *(const s8v*)&As[(wr + i * 16 + m) * 32 + q * 8];
#pragma unroll
        for (int c = 0; c < 4; c++) bg[c] = *(const s8v*)&Bs[(wc + c * 16 + m) * 32 + q * 8];
#pragma unroll
        for (int i = 0; i < 4; i++)
#pragma unroll
            for (int c = 0; c < 4; c++)   // SWAPPED operands: acc holds C^T fragment
                acc[i][c] = __builtin_amdgcn_mfma_f32_16x16x32_bf16(bg[c], af[i], acc[i][c], 0, 0, 0);
    }

    // epilogue: value(lane,reg r) = C[row0+wr+i*16+m][col0+wc+c*16+q*4+r]
#pragma unroll
    for (int c = 0; c < 4; c++) {
        int gcb = col0 + wc + c * 16;             // 16-col tile: SEGW mult of 16 => single segment
        if (gcb < SEGW * NSEG) {
            int seg = gcb / SEGW;
            int colb = gcb - seg * SEGW + q * 4;  // + r (r=0..3 contiguous)
            ushort* op = seg == 0 ? o0 : (seg == 1 ? o1 : o2);
#pragma unroll
            for (int i = 0; i < 4; i++) {
                int gr = row0 + wr + i * 16 + m;
                if (gr < NN) {
                    ushort4 s4;
                    s4.x = bf16_of_float(acc[i][c][0]);
                    s4.y = bf16_of_float(acc[i][c][1]);
                    s4.z = bf16_of_float(acc[i][c][2]);
                    s4.w = bf16_of_float(acc[i][c][3]);
                    *(ushort4*)&op[(size_t)gr * SEGW + colb] = s4;
                }
            }
        }
    }
}

// ---------------- fused GATv2 edge phase (+ final log-softmax), degree-sorted ----------------
// One wave per dst node (taken from order[]), all 4 heads. lane=16h+j holds dims
// [4j..4j+3] of head h. All features bf16. attn pre-scaled by log2(e) -> exp2f.
// NO readfirstlane on srcs (r11); NO fused BN stats (r9).

template<int DH, bool FINAL>
__global__ __launch_bounds__(256) void k_aggregate(const ushort* __restrict__ fs, const ushort* __restrict__ fd,
                                                   const ushort* __restrict__ res,
                                                   const ushort* __restrict__ attn,
                                                   const ushort* __restrict__ bias,
                                                   const int* __restrict__ indptr, const int* __restrict__ srcs,
                                                   const int* __restrict__ order,
                                                   ushort* __restrict__ outb, float* __restrict__ outf) {
    constexpr int F = HH * DH;
    constexpr int JMAX = DH >> 2;
    int tt = threadIdx.x;
    int v = __builtin_amdgcn_readfirstlane(order[blockIdx.x * 4 + (tt >> 6)]);
    int lane = tt & 63;
    int h = lane >> 4, j = lane & 15;
    bool act = j < JMAX;
    unsigned off = h * DH + 4 * j;
    unsigned vbase = (unsigned)v * F + off;
    float2 fda = {0.f,0.f}, fdb = {0.f,0.f}, ava = {0.f,0.f}, avb = {0.f,0.f};
    if (act) {
        uint2 d = *(const uint2*)&fd[vbase];
        fda = cvt2(d.x); fdb = cvt2(d.y);
        uint2 a = *(const uint2*)&attn[off];
        const float LOG2E = 1.4426950408889634f;
        ava = f2muls(cvt2(a.x), LOG2E); avb = f2muls(cvt2(a.y), LOG2E);
    }
    float l = 0.f;
    float2 acca = {0.f,0.f}, accb = {0.f,0.f};
    int beg = indptr[v], end = indptr[v + 1];

    auto ldrow = [&](int u, float2& ra, float2& rb) {
        ra = make_float2(0.f, 0.f); rb = make_float2(0.f, 0.f);
        if (act) {
            uint2 d = *(const uint2*)&fs[(unsigned)u * F + off];
            ra = cvt2(d.x); rb = cvt2(d.y);
        }
    };
    auto dotlr = [&](const float2& ra, const float2& rb) -> float {
        float2 t0 = f2add(ra, fda);
        float2 t1 = f2add(rb, fdb);
        t0 = f2max(t0, f2muls(t0, 0.2f));      // leaky_relu slope 0.2 == max(t, 0.2t)
        t1 = f2max(t1, f2muls(t1, 0.2f));
        float2 p2 = f2mul(ava, t0);
        p2 = f2fma(avb, t1, p2);
        return p2.x + p2.y;                    // log2-domain score
    };

    int i = beg;
    for (; i + 3 < end; i += 4) {
        int u0 = srcs[i], u1 = srcs[i+1], u2 = srcs[i+2], u3 = srcs[i+3];
        float2 r0a, r0b, r1a, r1b, r2a, r2b, r3a, r3b;
        ldrow(u0, r0a, r0b); ldrow(u1, r1a, r1b);
        ldrow(u2, r2a, r2b); ldrow(u3, r3a, r3b);
        float p0 = rowsum16(dotlr(r0a, r0b));
        float p1 = rowsum16(dotlr(r1a, r1b));
        float p2 = rowsum16(dotlr(r2a, r2b));
        float p3 = rowsum16(dotlr(r3a, r3b));
        float w0 = exp2f(p0), w1 = exp2f(p1), w2 = exp2f(p2), w3 = exp2f(p3);
        l += (w0 + w1) + (w2 + w3);
        acca = f2fma(make_float2(w0, w0), r0a, acca);
        accb = f2fma(make_float2(w0, w0), r0b, accb);
        acca = f2fma(make_float2(w1, w1), r1a, acca);
        accb = f2fma(make_float2(w1, w1), r1b, accb);
        acca = f2fma(make_float2(w2, w2), r2a, acca);
        accb = f2fma(make_float2(w2, w2), r2b, accb);
        acca = f2fma(make_float2(w3, w3), r3a, acca);
        accb = f2fma(make_float2(w3, w3), r3b, accb);
    }
    for (; i < end; i++) {
        float2 ra, rb;
        ldrow(srcs[i], ra, rb);
        float p0 = rowsum16(dotlr(ra, rb));
        float w0 = exp2f(p0);
        l += w0;
        acca = f2fma(make_float2(w0, w0), ra, acca);
        accb = f2fma(make_float2(w0, w0), rb, accb);
    }

    float4 o4 = {0.f, 0.f, 0.f, 0.f};
    if (act) {
        float inv = 1.f / fmaxf(l, 1e-9f);
        uint2 rr = *(const uint2*)&res[vbase];
        float2 rl = cvt2(rr.x), rh = cvt2(rr.y);
        uint2 bb = *(const uint2*)&bias[off];
        float2 bl = cvt2(bb.x), bh = cvt2(bb.y);
        o4.x = acca.x * inv + rl.x + bl.x;
        o4.y = acca.y * inv + rl.y + bl.y;
        o4.z = accb.x * inv + rh.x + bh.x;
        o4.w = accb.y * inv + rh.y + bh.y;
        if (!FINAL) {
            o4.x = fmaxf(o4.x, 0.f); o4.y = fmaxf(o4.y, 0.f);
            o4.z = fmaxf(o4.z, 0.f); o4.w = fmaxf(o4.w, 0.f);
        }
    }
    if (!FINAL) {
        if (act) {
            ushort4 s4;
            s4.x = bf16_of_float(o4.x); s4.y = bf16_of_float(o4.y);
            s4.z = bf16_of_float(o4.z); s4.w = bf16_of_float(o4.w);
            *(ushort4*)&outb[vbase] = s4;
        }
    } else {
        // head mean: sum over the 4 head groups (lanes 16/32 apart, same j)
#pragma unroll
        for (int msk = 16; msk <= 32; msk <<= 1) {
            o4.x += __shfl_xor(o4.x, msk, 64);
            o4.y += __shfl_xor(o4.y, msk, 64);
            o4.z += __shfl_xor(o4.z, msk, 64);
            o4.w += __shfl_xor(o4.w, msk, 64);
        }
        float4 zv = make_float4(0.25f * o4.x, 0.25f * o4.y, 0.25f * o4.z, 0.25f * o4.w);
        float mx4 = act ? fmaxf(fmaxf(zv.x, zv.y), fmaxf(zv.z, zv.w)) : -1e30f;
        float mx = rowmax16(mx4);
        float es = 0.f;
        if (act) es = __expf(zv.x - mx) + __expf(zv.y - mx) + __expf(zv.z - mx) + __expf(zv.w - mx);
        float ssum = rowsum16(es);
        float lse = mx + logf(ssum);
        if (act && h == 0) {
            float4 w4 = make_float4(zv.x - lse, zv.y - lse, zv.z - lse, zv.w - lse);
            *(float4*)&outf[(size_t)v * CC + 4 * j] = w4;
        }
    }
}

// ---------------- batchnorm stats (bf16 in), r8-proven structure: 60k global atomics ----------------

__global__ __launch_bounds__(256) void k_bn_partial(const ushort* __restrict__ h, float* __restrict__ sum,
                                                    float* __restrict__ sumsq) {
    int c = threadIdx.x;
    int r0 = blockIdx.x * 128;
    int r1 = min(NN, r0 + 128);
    float s = 0.f, ss = 0.f;
    for (int r = r0; r < r1; r++) {
        float vv = b2f(h[(size_t)r * HD + c]);
        s += vv; ss += vv * vv;
    }
    atomicAdd(&sum[c], s);
    atomicAdd(&sumsq[c], ss);
}

// ---------------- batchnorm normalize (bf16 in, bf16 out), x4 vectorized ----------------

__global__ __launch_bounds__(256) void k_bn_norm(const ushort* __restrict__ hin, const float* __restrict__ sum,
                                                 const float* __restrict__ sumsq,
                                                 const ushort* __restrict__ g,
                                                 const ushort* __restrict__ be,
                                                 ushort* __restrict__ hbf) {
    int i4 = blockIdx.x * 256 + threadIdx.x;
    if (i4 < NN * HD / 4) {
        int base = i4 * 4;
        int c = base & (HD - 1);
        ushort4 hv = ((const ushort4*)hin)[i4];
        ushort4 ov;
        float vv[4] = {b2f(hv.x), b2f(hv.y), b2f(hv.z), b2f(hv.w)};
        ushort* po = (ushort*)&ov;
#pragma unroll
        for (int k = 0; k < 4; k++) {
            float mean = sum[c + k] * (1.0f / NN);
            float var = fmaxf(sumsq[c + k] * (1.0f / NN) - mean * mean, 0.f);
            float y = b2f(g[c + k]) * (vv[k] - mean) * rsqrtf(var + 1e-5f) + b2f(be[c + k]);
            po[k] = bf16_of_float(fmaxf(y, 0.f));
        }
        ((ushort4*)hbf)[i4] = ov;
    }
}

// ---------------- driver ----------------

static inline char* alignup(char* p) { return (char*)(((size_t)p + 255) & ~(size_t)255); }

extern "C" void kernel_launch(void* const* d_in, const int* in_sizes, int n_in,
                              void* d_out, int out_size, void* d_ws, size_t ws_size,
                              hipStream_t stream) {
    const float* x     = (const float*)d_in[0];
    const int*  src    = (const int*)d_in[1];
    const int*  dst    = (const int*)d_in[2];
    const float* Wsrc0 = (const float*)d_in[3];
    const float* Wdst0 = (const float*)d_in[4];
    const float* b0    = (const float*)d_in[5];
    const float* attn0 = (const float*)d_in[6];
    const float* resW0 = (const float*)d_in[7];
    const float* Wsrc1 = (const float*)d_in[8];
    const float* Wdst1 = (const float*)d_in[9];
    const float* b1    = (const float*)d_in[10];
    const float* attn1 = (const float*)d_in[11];
    const float* Wsrc2 = (const float*)d_in[12];
    const float* Wdst2 = (const float*)d_in[13];
    const float* b2    = (const float*)d_in[14];
    const float* attn2 = (const float*)d_in[15];
    const float* resW2 = (const float*)d_in[16];
    const float* g0    = (const float*)d_in[17];
    const float* be0   = (const float*)d_in[18];
    const float* g1    = (const float*)d_in[19];
    const float* be1   = (const float*)d_in[20];

    char* w = (char*)d_ws;
    const size_t NF = (size_t)NN * HD;
    ushort* fsb = (ushort*)w; w += NF * 2;
    ushort* fdb = (ushort*)w; w += NF * 2;
    ushort* resb= (ushort*)w; w += NF * 2;
    ushort* hag = (ushort*)w; w += NF * 2;
    ushort* hbf = (ushort*)w; w += NF * 2;
    ushort* xc  = (ushort*)w; w += (size_t)NN * INP * 2;
    ushort* bt0 = (ushort*)w; w += 768 * 128 * 2;   // 3 segs [256x128]
    ushort* bt1 = (ushort*)w; w += 512 * 256 * 2;   // 2 segs [256x256]
    ushort* bt2 = (ushort*)w; w += 512 * 256 * 2;   // packed 3x160 + 32 pad rows, K=256
    ushort* smallv = (ushort*)w; w += 2368 * 2; w = alignup(w);
    // zeroed in k_prep: bnstats[1024] + cnt[NN] + pos[NN] + binCnt[64] + binRes[64]
    float* bnstats = (float*)w; w += 1024 * 4;
    int* cnt    = (int*)w; w += NN * 4;
    int* pos    = (int*)w; w += NN * 4;
    int* binCnt = (int*)w; w += 64 * 4;
    int* binRes = (int*)w; w += 64 * 4; w = alignup(w);
    int* indptr = (int*)w; w += (NN + 1) * 4; w = alignup(w);
    int* order  = (int*)w; w += NN * 4; w = alignup(w);
    int* srcs   = (int*)w; w += EE * 4;

    const ushort* c_b0    = smallv + 0;
    const ushort* c_attn0 = smallv + 256;
    const ushort* c_b1    = smallv + 512;
    const ushort* c_attn1 = smallv + 768;
    const ushort* c_b2    = smallv + 1024;
    const ushort* c_attn2 = smallv + 1184;
    const ushort* c_g0    = smallv + 1344;
    const ushort* c_be0   = smallv + 1600;
    const ushort* c_g1    = smallv + 1856;
    const ushort* c_be1   = smallv + 2112;

    // 1: fused prep
    k_prep<<<XB + TB + ZB + 1, 256, 0, stream>>>(x, xc,
        Wsrc0, Wdst0, resW0, Wsrc1, Wdst1, Wsrc2, Wdst2, resW2, bt0, bt1, bt2,
        (int*)bnstats,
        b0, attn0, b1, attn1, b2, attn2, g0, be0, g1, be1, smallv);

    // 2-6: CSR build + cheap parallel degree sort
    const int NB = (NN + 255) / 256;   // 118
    k_hist<<<(EE + 255) / 256, 256, 0, stream>>>(dst, cnt);
    k_binhist<<<NB, 256, 0, stream>>>(cnt, binCnt);
    k_scan<<<1, 1024, 0, stream>>>(cnt, indptr, binCnt, binRes);
    k_order<<<NB, 256, 0, stream>>>(cnt, binRes, order);
    k_scatter<<<(EE + 255) / 256, 256, 0, stream>>>(src, dst, indptr, pos, srcs);

    const int MB = (NN + 127) / 128;   // 235

    // 7-10: layer 0
    k_gemm_tiled<128, 256, 3><<<dim3(MB, 6), 256, 0, stream>>>(xc, bt0, fsb, fdb, resb);
    k_aggregate<DD, false><<<NN / 4, 256, 0, stream>>>(fsb, fdb, resb, c_attn0, c_b0,
        indptr, srcs, order, hag, nullptr);
    k_bn_partial<<<MB, 256, 0, stream>>>(hag, bnstats, bnstats + 256);
    k_bn_norm<<<(int)((NF / 4 + 255) / 256), 256, 0, stream>>>(hag, bnstats, bnstats + 256,
                                                               c_g0, c_be0, hbf);

    // 11-14: layer 1 (identity residual = hbf)
    k_gemm_tiled<256, 256, 2><<<dim3(MB, 4), 256, 0, stream>>>(hbf, bt1, fsb, fdb, nullptr);
    k_aggregate<DD, false><<<NN / 4, 256, 0, stream>>>(fsb, fdb, hbf, c_attn1, c_b1,
        indptr, srcs, order, hag, nullptr);
    k_bn_partial<<<MB, 256, 0, stream>>>(hag, bnstats + 512, bnstats + 768);
    k_bn_norm<<<(int)((NF / 4 + 255) / 256), 256, 0, stream>>>(hag, bnstats + 512, bnstats + 768,
                                                               c_g1, c_be1, hbf);

    // 15-16: layer 2 (packed 160-col segments) + fused head-mean/log_softmax -> d_out
    k_gemm_tiled<256, 160, 3><<<dim3(MB, 4), 256, 0, stream>>>(hbf, bt2, fsb, fdb, resb);
    k_aggregate<CC, true><<<NN / 4, 256, 0, stream>>>(fsb, fdb, resb, c_attn2, c_b2,
        indptr, srcs, order, nullptr, (float*)d_out);
}

// Round 16
// 412.191 us; speedup vs baseline: 1.1501x; 1.0818x over previous
//
#include <hip/hip_runtime.h>
#include <hip/hip_bf16.h>
#include <math.h>

#define NN 30000
#define EE 400000
#define INP 128
#define HH 4
#define DD 64
#define CC 40
#define HD 256   // H*D
#define HC 160   // H*C

typedef unsigned short ushort;
typedef __attribute__((ext_vector_type(8))) short s8v;   // 8 x bf16 bits (4 VGPRs)
typedef __attribute__((ext_vector_type(4))) float f4v;   // MFMA accumulator

// Inputs: fp32 storage holding bf16-rounded values (established r1-r4).

__device__ inline ushort bf16_of_float(float f) {
    __hip_bfloat16 b = __float2bfloat16(f);
    return *(ushort*)&b;
}
// dword holding 2 packed bf16 -> 2 fp32 (low half, high half)
__device__ __forceinline__ float2 cvt2(unsigned d) {
    return make_float2(__uint_as_float(d << 16), __uint_as_float(d & 0xFFFF0000u));
}
__device__ __forceinline__ float b2f(ushort u) { return __uint_as_float(((unsigned)u) << 16); }

// float2 helpers (packable to v_pk_*_f32)
__device__ __forceinline__ float2 f2add(float2 a, float2 b){ return make_float2(a.x+b.x, a.y+b.y); }
__device__ __forceinline__ float2 f2mul(float2 a, float2 b){ return make_float2(a.x*b.x, a.y*b.y); }
__device__ __forceinline__ float2 f2muls(float2 a, float s){ return make_float2(a.x*s, a.y*s); }
__device__ __forceinline__ float2 f2max(float2 a, float2 b){ return make_float2(fmaxf(a.x,b.x), fmaxf(a.y,b.y)); }
__device__ __forceinline__ float2 f2fma(float2 a, float2 b, float2 c){
    return make_float2(__fmaf_rn(a.x,b.x,c.x), __fmaf_rn(a.y,b.y,c.y));
}

// async 16B global->LDS (dest = wave-uniform base + lane*16)
__device__ __forceinline__ void gld16(const void* g, void* l) {
    __builtin_amdgcn_global_load_lds((const __attribute__((address_space(1))) void*)g,
                                     (__attribute__((address_space(3))) void*)l, 16, 0, 0);
}

// 16-lane DPP row reductions (VALU-only)
__device__ __forceinline__ float rowsum16(float x) {
    int t;
    t = __builtin_amdgcn_update_dpp(0, __float_as_int(x), 0x128, 0xF, 0xF, false); x += __int_as_float(t);
    t = __builtin_amdgcn_update_dpp(0, __float_as_int(x), 0x124, 0xF, 0xF, false); x += __int_as_float(t);
    t = __builtin_amdgcn_update_dpp(0, __float_as_int(x), 0x122, 0xF, 0xF, false); x += __int_as_float(t);
    t = __builtin_amdgcn_update_dpp(0, __float_as_int(x), 0x121, 0xF, 0xF, false); x += __int_as_float(t);
    return x;
}
__device__ __forceinline__ float rowmax16(float x) {
    int t;
    t = __builtin_amdgcn_update_dpp(0, __float_as_int(x), 0x128, 0xF, 0xF, false); x = fmaxf(x, __int_as_float(t));
    t = __builtin_amdgcn_update_dpp(0, __float_as_int(x), 0x124, 0xF, 0xF, false); x = fmaxf(x, __int_as_float(t));
    t = __builtin_amdgcn_update_dpp(0, __float_as_int(x), 0x122, 0xF, 0xF, false); x = fmaxf(x, __int_as_float(t));
    t = __builtin_amdgcn_update_dpp(0, __float_as_int(x), 0x121, 0xF, 0xF, false); x = fmaxf(x, __int_as_float(t));
    return x;
}

// ---------------- fused prep: x-cast + weight transposes (packed bt2) + zeroing + small vecs ----------------
#define XB 3750   // ceil(960000/256)
#define TB 1408   // ceil(360448/256)
#define ZB 240    // ceil((1024+2*NN+192)/256)

__global__ __launch_bounds__(256) void k_prep(const float* __restrict__ x, ushort* __restrict__ xc,
        const float* W0, const float* W1, const float* W2, const float* W3,
        const float* W4, const float* W5, const float* W6, const float* W7,
        ushort* bt0, ushort* bt1, ushort* bt2,
        int* __restrict__ zero_region,
        const float* b0, const float* a0, const float* b1, const float* a1,
        const float* b2, const float* a2, const float* g0, const float* be0,
        const float* g1, const float* be1, ushort* __restrict__ smallv) {
    int b = blockIdx.x, t = threadIdx.x;
    if (b < XB) {
        int i = b * 256 + t;
        if (i < NN * INP / 4) {
            float4 v = ((const float4*)x)[i];
            ushort4 o;
            o.x = bf16_of_float(v.x); o.y = bf16_of_float(v.y);
            o.z = bf16_of_float(v.z); o.w = bf16_of_float(v.w);
            ((ushort4*)xc)[i] = o;
        }
    } else if (b < XB + TB) {
        const float* Ws[8] = {W0, W1, W2, W3, W4, W5, W6, W7};
        int g = (b - XB) * 256 + t;               // < 360448
        if (g < 98304) {                          // bt0: 3 segs of [256 x 128]
            int seg = g >> 15, local = g & 32767;
            int n = local >> 7, k = local & 127;
            bt0[g] = bf16_of_float(Ws[seg][k * 256 + n]);
        } else if (g < 229376) {                  // bt1: 2 segs of [256 x 256]
            int gg = g - 98304;
            int seg = gg >> 16, local = gg & 65535;
            int n = local >> 8, k = local & 255;
            bt1[gg] = bf16_of_float(Ws[3 + seg][k * 256 + n]);
        } else if (g < 360448) {                  // bt2: packed [512 x 256], rows = 3x160 + 32 pad
            int gg = g - 229376;
            int n = gg >> 8, k = gg & 255;
            ushort val = 0;
            if (n < 480) {
                int seg = n / 160;
                int nn = n - seg * 160;
                val = bf16_of_float(Ws[5 + seg][k * 160 + nn]);
            }
            bt2[gg] = val;
        }
    } else if (b < XB + TB + ZB) {
        int i = (b - XB - TB) * 256 + t;
        if (i < 1024 + 2 * NN + 192) zero_region[i] = 0;   // bnstats+cnt+pos+binCnt+binPos+total
    } else {
        const float* ptrs[10] = {b0, a0, b1, a1, b2, a2, g0, be0, g1, be1};
        const int sz[10] = {256, 256, 256, 256, 160, 160, 256, 256, 256, 256};
        int off = 0;
        for (int j = 0; j < 10; j++) {
            if (t < sz[j]) smallv[off + t] = bf16_of_float(ptrs[j][t]);
            off += sz[j];
        }
    }
}

// ---------------- CSR build (range-assignment form) + parallel degree sort ----------------
// beg[v] is ANY disjoint range base with length cnt[v] -- no global prefix order needed.

__global__ __launch_bounds__(256) void k_hist(const int* __restrict__ dst, int* __restrict__ cnt) {
    int e = blockIdx.x * 256 + threadIdx.x;
    if (e < EE) atomicAdd(&cnt[dst[e]], 1);
}

// global 64-bin degree histogram (LDS pre-aggregated; <=64 global atomics/block)
__global__ __launch_bounds__(256) void k_binhist(const int* __restrict__ cnt, int* __restrict__ binCnt) {
    __shared__ int lb[64];
    int t = threadIdx.x;
    if (t < 64) lb[t] = 0;
    __syncthreads();
    int i = blockIdx.x * 256 + t;
    if (i < NN) atomicAdd(&lb[63 - min(cnt[i], 63)], 1);   // bin 0 = highest degree
    __syncthreads();
    if (t < 64 && lb[t] > 0) atomicAdd(&binCnt[t], lb[t]);
}

// parallel range assignment: block-local scan + one total-counter atomic per block
__global__ __launch_bounds__(256) void k_beg(const int* __restrict__ cnt, int* __restrict__ beg,
                                             int* __restrict__ total) {
    __shared__ int ss[256];
    __shared__ int base;
    int t = threadIdx.x;
    int i = blockIdx.x * 256 + t;
    int c = (i < NN) ? cnt[i] : 0;
    ss[t] = c;
    __syncthreads();
    for (int o = 1; o < 256; o <<= 1) {
        int v = (t >= o) ? ss[t - o] : 0;
        __syncthreads();
        ss[t] += v;
        __syncthreads();
    }
    if (t == 255) base = atomicAdd(total, ss[255]);
    __syncthreads();
    if (i < NN) beg[i] = base + ss[t] - c;     // exclusive within-block + reserved base
}

// place nodes into order[] (in-block 64-bin prefix + per-bin reservation atomics)
__global__ __launch_bounds__(256) void k_order(const int* __restrict__ cnt, const int* __restrict__ binCnt,
                                               int* __restrict__ binPos, int* __restrict__ order) {
    __shared__ int lb[64], lbase[64], bpre[64];
    int t = threadIdx.x;
    if (t < 64) { lb[t] = 0; bpre[t] = binCnt[t]; }
    __syncthreads();
    int i = blockIdx.x * 256 + t;
    int bin = 0, rank = 0;
    if (i < NN) {
        bin = 63 - min(cnt[i], 63);
        rank = atomicAdd(&lb[bin], 1);
    }
    for (int o = 1; o < 64; o <<= 1) {         // in-LDS inclusive scan of binCnt
        int v = (t >= o && t < 64) ? bpre[t - o] : 0;
        __syncthreads();
        if (t < 64) bpre[t] += v;
        __syncthreads();
    }
    if (t < 64 && lb[t] > 0)
        lbase[t] = bpre[t] - binCnt[t] + atomicAdd(&binPos[t], lb[t]);   // exclusive base + reservation
    __syncthreads();
    if (i < NN) order[lbase[bin] + rank] = i;
}

__global__ __launch_bounds__(256) void k_scatter(const int* __restrict__ src, const int* __restrict__ dst,
                                                 const int* __restrict__ beg, int* __restrict__ pos,
                                                 int* __restrict__ srcs) {
    int e = blockIdx.x * 256 + threadIdx.x;
    if (e < EE) {
        int d = dst[e];
        int p = atomicAdd(&pos[d], 1);
        srcs[beg[d] + p] = src[e];
    }
}

// ---------------- tiled bf16 MFMA GEMM, single-buffer staging (r10-proven) ----------------
// 128x128 tile, 4 waves, BK=32. MFMA operands SWAPPED (bg, af): acc holds the
// transposed fragment -- lane&15 = output ROW, regs = 4 consecutive output COLS
// -> each acc[i][c] packs to one ushort4 store (16 stores/lane vs 64).

template<int K, int SEGW, int NSEG>
__global__ __launch_bounds__(256) void k_gemm_tiled(const ushort* __restrict__ A,
                                                    const ushort* __restrict__ Bt,
                                                    ushort* __restrict__ o0, ushort* __restrict__ o1,
                                                    ushort* __restrict__ o2) {
    __shared__ ushort As[128 * 32];   // chunk c (16B) at byte c*16; row = c>>2, kpart = c&3
    __shared__ ushort Bs[128 * 32];
    int t = threadIdx.x;
    int wave = t >> 6, lane = t & 63;
    int m = lane & 15, q = lane >> 4;
    int row0 = blockIdx.x * 128, col0 = blockIdx.y * 128;
    int wr = (wave >> 1) << 6, wc = (wave & 1) << 6;
    f4v acc[4][4] = {};
    int c1 = t, c2 = t + 256;
    int ar1 = min(row0 + (c1 >> 2), NN - 1);
    int ar2 = min(row0 + (c2 >> 2), NN - 1);
    const ushort* a1 = A + (size_t)ar1 * K + (c1 & 3) * 8;
    const ushort* a2 = A + (size_t)ar2 * K + (c2 & 3) * 8;
    const ushort* b1 = Bt + (size_t)(col0 + (c1 >> 2)) * K + (c1 & 3) * 8;
    const ushort* b2 = Bt + (size_t)(col0 + (c2 >> 2)) * K + (c2 & 3) * 8;
    int wbase = wave << 10;
    char* AsB = (char*)As;
    char* BsB = (char*)Bs;

#pragma unroll
    for (int kt = 0; kt < K; kt += 32) {
        __syncthreads();
        gld16(a1 + kt, AsB + wbase);
        gld16(a2 + kt, AsB + 4096 + wbase);
        gld16(b1 + kt, BsB + wbase);
        gld16(b2 + kt, BsB + 4096 + wbase);
        __syncthreads();
        s8v af[4], bg[4];
#pragma unroll
        for (int i = 0; i < 4; i++) af[i] = *(const s8v*)&As[(wr + i * 16 + m) * 32 + q * 8];
#pragma unroll
        for (int c = 0; c < 4; c++) bg[c] = *(const s8v*)&Bs[(wc + c * 16 + m) * 32 + q * 8];
#pragma unroll
        for (int i = 0; i < 4; i++)
#pragma unroll
            for (int c = 0; c < 4; c++)   // SWAPPED operands: acc holds C^T fragment
                acc[i][c] = __builtin_amdgcn_mfma_f32_16x16x32_bf16(bg[c], af[i], acc[i][c], 0, 0, 0);
    }

    // epilogue: value(lane,reg r) = C[row0+wr+i*16+m][col0+wc+c*16+q*4+r]
#pragma unroll
    for (int c = 0; c < 4; c++) {
        int gcb = col0 + wc + c * 16;             // 16-col tile: SEGW mult of 16 => single segment
        if (gcb < SEGW * NSEG) {
            int seg = gcb / SEGW;
            int colb = gcb - seg * SEGW + q * 4;  // + r (r=0..3 contiguous)
            ushort* op = seg == 0 ? o0 : (seg == 1 ? o1 : o2);
#pragma unroll
            for (int i = 0; i < 4; i++) {
                int gr = row0 + wr + i * 16 + m;
                if (gr < NN) {
                    ushort4 s4;
                    s4.x = bf16_of_float(acc[i][c][0]);
                    s4.y = bf16_of_float(acc[i][c][1]);
                    s4.z = bf16_of_float(acc[i][c][2]);
                    s4.w = bf16_of_float(acc[i][c][3]);
                    *(ushort4*)&op[(size_t)gr * SEGW + colb] = s4;
                }
            }
        }
    }
}

// ---------------- fused GATv2 edge phase (+ final log-softmax), degree-sorted ----------------
// One wave per dst node (taken from order[]), all 4 heads. lane=16h+j holds dims
// [4j..4j+3] of head h. All features bf16. attn pre-scaled by log2(e) -> exp2f.
// Ranges via beg[]+cnt[] (no prefix CSR). NO readfirstlane on srcs (r11);
// NO fused BN stats (r9).

template<int DH, bool FINAL>
__global__ __launch_bounds__(256) void k_aggregate(const ushort* __restrict__ fs, const ushort* __restrict__ fd,
                                                   const ushort* __restrict__ res,
                                                   const ushort* __restrict__ attn,
                                                   const ushort* __restrict__ bias,
                                                   const int* __restrict__ beg, const int* __restrict__ cnt,
                                                   const int* __restrict__ srcs,
                                                   const int* __restrict__ order,
                                                   ushort* __restrict__ outb, float* __restrict__ outf) {
    constexpr int F = HH * DH;
    constexpr int JMAX = DH >> 2;
    int tt = threadIdx.x;
    int v = __builtin_amdgcn_readfirstlane(order[blockIdx.x * 4 + (tt >> 6)]);
    int lane = tt & 63;
    int h = lane >> 4, j = lane & 15;
    bool act = j < JMAX;
    unsigned off = h * DH + 4 * j;
    unsigned vbase = (unsigned)v * F + off;
    float2 fda = {0.f,0.f}, fdb = {0.f,0.f}, ava = {0.f,0.f}, avb = {0.f,0.f};
    if (act) {
        uint2 d = *(const uint2*)&fd[vbase];
        fda = cvt2(d.x); fdb = cvt2(d.y);
        uint2 a = *(const uint2*)&attn[off];
        const float LOG2E = 1.4426950408889634f;
        ava = f2muls(cvt2(a.x), LOG2E); avb = f2muls(cvt2(a.y), LOG2E);
    }
    float l = 0.f;
    float2 acca = {0.f,0.f}, accb = {0.f,0.f};
    int b0i = beg[v], end = b0i + cnt[v];

    auto ldrow = [&](int u, float2& ra, float2& rb) {
        ra = make_float2(0.f, 0.f); rb = make_float2(0.f, 0.f);
        if (act) {
            uint2 d = *(const uint2*)&fs[(unsigned)u * F + off];
            ra = cvt2(d.x); rb = cvt2(d.y);
        }
    };
    auto dotlr = [&](const float2& ra, const float2& rb) -> float {
        float2 t0 = f2add(ra, fda);
        float2 t1 = f2add(rb, fdb);
        t0 = f2max(t0, f2muls(t0, 0.2f));      // leaky_relu slope 0.2 == max(t, 0.2t)
        t1 = f2max(t1, f2muls(t1, 0.2f));
        float2 p2 = f2mul(ava, t0);
        p2 = f2fma(avb, t1, p2);
        return p2.x + p2.y;                    // log2-domain score
    };

    int i = b0i;
    for (; i + 3 < end; i += 4) {
        int u0 = srcs[i], u1 = srcs[i+1], u2 = srcs[i+2], u3 = srcs[i+3];
        float2 r0a, r0b, r1a, r1b, r2a, r2b, r3a, r3b;
        ldrow(u0, r0a, r0b); ldrow(u1, r1a, r1b);
        ldrow(u2, r2a, r2b); ldrow(u3, r3a, r3b);
        float p0 = rowsum16(dotlr(r0a, r0b));
        float p1 = rowsum16(dotlr(r1a, r1b));
        float p2 = rowsum16(dotlr(r2a, r2b));
        float p3 = rowsum16(dotlr(r3a, r3b));
        float w0 = exp2f(p0), w1 = exp2f(p1), w2 = exp2f(p2), w3 = exp2f(p3);
        l += (w0 + w1) + (w2 + w3);
        acca = f2fma(make_float2(w0, w0), r0a, acca);
        accb = f2fma(make_float2(w0, w0), r0b, accb);
        acca = f2fma(make_float2(w1, w1), r1a, acca);
        accb = f2fma(make_float2(w1, w1), r1b, accb);
        acca = f2fma(make_float2(w2, w2), r2a, acca);
        accb = f2fma(make_float2(w2, w2), r2b, accb);
        acca = f2fma(make_float2(w3, w3), r3a, acca);
        accb = f2fma(make_float2(w3, w3), r3b, accb);
    }
    for (; i < end; i++) {
        float2 ra, rb;
        ldrow(srcs[i], ra, rb);
        float p0 = rowsum16(dotlr(ra, rb));
        float w0 = exp2f(p0);
        l += w0;
        acca = f2fma(make_float2(w0, w0), ra, acca);
        accb = f2fma(make_float2(w0, w0), rb, accb);
    }

    float4 o4 = {0.f, 0.f, 0.f, 0.f};
    if (act) {
        float inv = 1.f / fmaxf(l, 1e-9f);
        uint2 rr = *(const uint2*)&res[vbase];
        float2 rl = cvt2(rr.x), rh = cvt2(rr.y);
        uint2 bb = *(const uint2*)&bias[off];
        float2 bl = cvt2(bb.x), bh = cvt2(bb.y);
        o4.x = acca.x * inv + rl.x + bl.x;
        o4.y = acca.y * inv + rl.y + bl.y;
        o4.z = accb.x * inv + rh.x + bh.x;
        o4.w = accb.y * inv + rh.y + bh.y;
        if (!FINAL) {
            o4.x = fmaxf(o4.x, 0.f); o4.y = fmaxf(o4.y, 0.f);
            o4.z = fmaxf(o4.z, 0.f); o4.w = fmaxf(o4.w, 0.f);
        }
    }
    if (!FINAL) {
        if (act) {
            ushort4 s4;
            s4.x = bf16_of_float(o4.x); s4.y = bf16_of_float(o4.y);
            s4.z = bf16_of_float(o4.z); s4.w = bf16_of_float(o4.w);
            *(ushort4*)&outb[vbase] = s4;
        }
    } else {
        // head mean: sum over the 4 head groups (lanes 16/32 apart, same j)
#pragma unroll
        for (int msk = 16; msk <= 32; msk <<= 1) {
            o4.x += __shfl_xor(o4.x, msk, 64);
            o4.y += __shfl_xor(o4.y, msk, 64);
            o4.z += __shfl_xor(o4.z, msk, 64);
            o4.w += __shfl_xor(o4.w, msk, 64);
        }
        float4 zv = make_float4(0.25f * o4.x, 0.25f * o4.y, 0.25f * o4.z, 0.25f * o4.w);
        float mx4 = act ? fmaxf(fmaxf(zv.x, zv.y), fmaxf(zv.z, zv.w)) : -1e30f;
        float mx = rowmax16(mx4);
        float es = 0.f;
        if (act) es = __expf(zv.x - mx) + __expf(zv.y - mx) + __expf(zv.z - mx) + __expf(zv.w - mx);
        float ssum = rowsum16(es);
        float lse = mx + logf(ssum);
        if (act && h == 0) {
            float4 w4 = make_float4(zv.x - lse, zv.y - lse, zv.z - lse, zv.w - lse);
            *(float4*)&outf[(size_t)v * CC + 4 * j] = w4;
        }
    }
}

// ---------------- batchnorm stats (bf16 in), r8-proven structure: 60k global atomics ----------------

__global__ __launch_bounds__(256) void k_bn_partial(const ushort* __restrict__ h, float* __restrict__ sum,
                                                    float* __restrict__ sumsq) {
    int c = threadIdx.x;
    int r0 = blockIdx.x * 128;
    int r1 = min(NN, r0 + 128);
    float s = 0.f, ss = 0.f;
    for (int r = r0; r < r1; r++) {
        float vv = b2f(h[(size_t)r * HD + c]);
        s += vv; ss += vv * vv;
    }
    atomicAdd(&sum[c], s);
    atomicAdd(&sumsq[c], ss);
}

// ---------------- batchnorm normalize (bf16 in, bf16 out), x4 vectorized ----------------

__global__ __launch_bounds__(256) void k_bn_norm(const ushort* __restrict__ hin, const float* __restrict__ sum,
                                                 const float* __restrict__ sumsq,
                                                 const ushort* __restrict__ g,
                                                 const ushort* __restrict__ be,
                                                 ushort* __restrict__ hbf) {
    int i4 = blockIdx.x * 256 + threadIdx.x;
    if (i4 < NN * HD / 4) {
        int base = i4 * 4;
        int c = base & (HD - 1);
        ushort4 hv = ((const ushort4*)hin)[i4];
        ushort4 ov;
        float vv[4] = {b2f(hv.x), b2f(hv.y), b2f(hv.z), b2f(hv.w)};
        ushort* po = (ushort*)&ov;
#pragma unroll
        for (int k = 0; k < 4; k++) {
            float mean = sum[c + k] * (1.0f / NN);
            float var = fmaxf(sumsq[c + k] * (1.0f / NN) - mean * mean, 0.f);
            float y = b2f(g[c + k]) * (vv[k] - mean) * rsqrtf(var + 1e-5f) + b2f(be[c + k]);
            po[k] = bf16_of_float(fmaxf(y, 0.f));
        }
        ((ushort4*)hbf)[i4] = ov;
    }
}

// ---------------- driver ----------------

static inline char* alignup(char* p) { return (char*)(((size_t)p + 255) & ~(size_t)255); }

extern "C" void kernel_launch(void* const* d_in, const int* in_sizes, int n_in,
                              void* d_out, int out_size, void* d_ws, size_t ws_size,
                              hipStream_t stream) {
    const float* x     = (const float*)d_in[0];
    const int*  src    = (const int*)d_in[1];
    const int*  dst    = (const int*)d_in[2];
    const float* Wsrc0 = (const float*)d_in[3];
    const float* Wdst0 = (const float*)d_in[4];
    const float* b0    = (const float*)d_in[5];
    const float* attn0 = (const float*)d_in[6];
    const float* resW0 = (const float*)d_in[7];
    const float* Wsrc1 = (const float*)d_in[8];
    const float* Wdst1 = (const float*)d_in[9];
    const float* b1    = (const float*)d_in[10];
    const float* attn1 = (const float*)d_in[11];
    const float* Wsrc2 = (const float*)d_in[12];
    const float* Wdst2 = (const float*)d_in[13];
    const float* b2    = (const float*)d_in[14];
    const float* attn2 = (const float*)d_in[15];
    const float* resW2 = (const float*)d_in[16];
    const float* g0    = (const float*)d_in[17];
    const float* be0   = (const float*)d_in[18];
    const float* g1    = (const float*)d_in[19];
    const float* be1   = (const float*)d_in[20];

    char* w = (char*)d_ws;
    const size_t NF = (size_t)NN * HD;
    ushort* fsb = (ushort*)w; w += NF * 2;
    ushort* fdb = (ushort*)w; w += NF * 2;
    ushort* resb= (ushort*)w; w += NF * 2;
    ushort* hag = (ushort*)w; w += NF * 2;
    ushort* hbf = (ushort*)w; w += NF * 2;
    ushort* xc  = (ushort*)w; w += (size_t)NN * INP * 2;
    ushort* bt0 = (ushort*)w; w += 768 * 128 * 2;   // 3 segs [256x128]
    ushort* bt1 = (ushort*)w; w += 512 * 256 * 2;   // 2 segs [256x256]
    ushort* bt2 = (ushort*)w; w += 512 * 256 * 2;   // packed 3x160 + 32 pad rows, K=256
    ushort* smallv = (ushort*)w; w += 2368 * 2; w = alignup(w);
    // zeroed in k_prep: bnstats[1024] + cnt[NN] + pos[NN] + binCnt[64] + binPos[64] + total[64]
    float* bnstats = (float*)w; w += 1024 * 4;
    int* cnt    = (int*)w; w += NN * 4;
    int* pos    = (int*)w; w += NN * 4;
    int* binCnt = (int*)w; w += 64 * 4;
    int* binPos = (int*)w; w += 64 * 4;
    int* total  = (int*)w; w += 64 * 4; w = alignup(w);
    int* beg    = (int*)w; w += NN * 4; w = alignup(w);
    int* order  = (int*)w; w += NN * 4; w = alignup(w);
    int* srcs   = (int*)w; w += EE * 4;

    const ushort* c_b0    = smallv + 0;
    const ushort* c_attn0 = smallv + 256;
    const ushort* c_b1    = smallv + 512;
    const ushort* c_attn1 = smallv + 768;
    const ushort* c_b2    = smallv + 1024;
    const ushort* c_attn2 = smallv + 1184;
    const ushort* c_g0    = smallv + 1344;
    const ushort* c_be0   = smallv + 1600;
    const ushort* c_g1    = smallv + 1856;
    const ushort* c_be1   = smallv + 2112;

    // 1: fused prep
    k_prep<<<XB + TB + ZB + 1, 256, 0, stream>>>(x, xc,
        Wsrc0, Wdst0, resW0, Wsrc1, Wdst1, Wsrc2, Wdst2, resW2, bt0, bt1, bt2,
        (int*)bnstats,
        b0, attn0, b1, attn1, b2, attn2, g0, be0, g1, be1, smallv);

    // 2-6: CSR range-assignment + parallel degree sort (all multi-block)
    const int NB = (NN + 255) / 256;   // 118
    k_hist<<<(EE + 255) / 256, 256, 0, stream>>>(dst, cnt);
    k_binhist<<<NB, 256, 0, stream>>>(cnt, binCnt);
    k_beg<<<NB, 256, 0, stream>>>(cnt, beg, total);
    k_order<<<NB, 256, 0, stream>>>(cnt, binCnt, binPos, order);
    k_scatter<<<(EE + 255) / 256, 256, 0, stream>>>(src, dst, beg, pos, srcs);

    const int MB = (NN + 127) / 128;   // 235

    // 7-10: layer 0
    k_gemm_tiled<128, 256, 3><<<dim3(MB, 6), 256, 0, stream>>>(xc, bt0, fsb, fdb, resb);
    k_aggregate<DD, false><<<NN / 4, 256, 0, stream>>>(fsb, fdb, resb, c_attn0, c_b0,
        beg, cnt, srcs, order, hag, nullptr);
    k_bn_partial<<<MB, 256, 0, stream>>>(hag, bnstats, bnstats + 256);
    k_bn_norm<<<(int)((NF / 4 + 255) / 256), 256, 0, stream>>>(hag, bnstats, bnstats + 256,
                                                               c_g0, c_be0, hbf);

    // 11-14: layer 1 (identity residual = hbf)
    k_gemm_tiled<256, 256, 2><<<dim3(MB, 4), 256, 0, stream>>>(hbf, bt1, fsb, fdb, nullptr);
    k_aggregate<DD, false><<<NN / 4, 256, 0, stream>>>(fsb, fdb, hbf, c_attn1, c_b1,
        beg, cnt, srcs, order, hag, nullptr);
    k_bn_partial<<<MB, 256, 0, stream>>>(hag, bnstats + 512, bnstats + 768);
    k_bn_norm<<<(int)((NF / 4 + 255) / 256), 256, 0, stream>>>(hag, bnstats + 512, bnstats + 768,
                                                               c_g1, c_be1, hbf);

    // 15-16: layer 2 (packed 160-col segments) + fused head-mean/log_softmax -> d_out
    k_gemm_tiled<256, 160, 3><<<dim3(MB, 4), 256, 0, stream>>>(hbf, bt2, fsb, fdb, resb);
    k_aggregate<CC, true><<<NN / 4, 256, 0, stream>>>(fsb, fdb, resb, c_attn2, c_b2,
        beg, cnt, srcs, order, nullptr, (float*)d_out);
}